// Round 2
// baseline (318.573 us; speedup 1.0000x reference)
//
#include <hip/hip_runtime.h>
#include <hip/hip_bf16.h>
#include <cstdint>

#define N_TOK 4096
#define KTOP  64
#define DIM   1024
#define NLAT  16384
#define NCHUNK 8      // 128 cols/chunk -> 4 MB bf16 per chunk == one XCD L2

typedef __bf16 bf16x8 __attribute__((ext_vector_type(8)));
typedef float  floatx4 __attribute__((ext_vector_type(4)));
typedef float  f32x4   __attribute__((ext_vector_type(4)));
typedef unsigned int   u32x2   __attribute__((ext_vector_type(2)));
typedef unsigned short ushortx8 __attribute__((ext_vector_type(8)));

#define GLOBAL_AS(p) ((const __attribute__((address_space(1))) void*)(p))
#define LDS_AS(p)    ((__attribute__((address_space(3))) void*)(p))

__device__ inline unsigned short f2bf(float f){
  unsigned int u = __float_as_uint(f);
  unsigned int r = (u + 0x7fffu + ((u >> 16) & 1u)) >> 16;  // RNE
  return (unsigned short)r;
}
__device__ inline float bflo(unsigned int u){ return __uint_as_float(u << 16); }
__device__ inline float bfhi(unsigned int u){ return __uint_as_float(u & 0xffff0000u); }

// read 8 consecutive f32 (2x float4), write one 16B ushort8 bf16 store
__device__ inline void cvt8(const float* __restrict__ src, unsigned short* __restrict__ dst){
  float4 a = ((const float4*)src)[0];
  float4 b = ((const float4*)src)[1];
  ushortx8 o;
  o[0] = f2bf(a.x); o[1] = f2bf(a.y); o[2] = f2bf(a.z); o[3] = f2bf(a.w);
  o[4] = f2bf(b.x); o[5] = f2bf(b.y); o[6] = f2bf(b.z); o[7] = f2bf(b.w);
  *(ushortx8*)dst = o;
}

// Roles: [0,1024) x->bf16 | [1024,1280) Wskip->bf16 | [1280,5376) Wdec->chunked bf16
//        [5376,5440) act precompute | 5440: zero accumulators
__global__ __launch_bounds__(256) void prep(
    const float* __restrict__ x, const float* __restrict__ Wsk,
    const float* __restrict__ Wd,
    const float* __restrict__ la, const int* __restrict__ li,
    const float* __restrict__ pe, const float* __restrict__ pes,
    unsigned short* __restrict__ xb, unsigned short* __restrict__ wb,
    unsigned short* __restrict__ wdc,
    uint2* __restrict__ actbuf, float* __restrict__ accs){
  const int b = blockIdx.x;
  const int t = threadIdx.x;
  if (b < 1024){
    #pragma unroll
    for (int i = 0; i < 2; i++){
      int idx = b * 4096 + i * 2048 + t * 8;
      cvt8(x + idx, xb + idx);
    }
  } else if (b < 1280){
    #pragma unroll
    for (int i = 0; i < 2; i++){
      int idx = (b - 1024) * 4096 + i * 2048 + t * 8;
      cvt8(Wsk + idx, wb + idx);
    }
  } else if (b < 5376){
    const int j = t & 127;          // 128 threads per row, 8 floats each
    const int chunk = j >> 4;
    #pragma unroll
    for (int i = 0; i < 2; i++){
      int lat = (b - 1280) * 4 + i * 2 + (t >> 7);
      cvt8(Wd + (size_t)lat * DIM + j * 8,
           wdc + ((size_t)chunk * NLAT + lat) * 128 + (j & 15) * 8);
    }
  } else if (b < 5440){
    int e0 = (b - 5376) * 4096 + t;
    #pragma unroll
    for (int i = 0; i < 16; i++){
      int e = e0 + i * 256;
      int id = li[e];
      float a = (la[e] + pe[id]) * pes[id];
      actbuf[e] = make_uint2(__float_as_uint(a), (unsigned)id * 256u);
    }
  } else {
    for (int i = t; i < 1056; i += 256) accs[i] = 0.f;  // sse, sumsq, ticket, colsum
  }
}

// 128 rows x 64 cols tile -> 512 blocks (2 blocks/CU). m97-style staging. (unchanged)
__global__ __launch_bounds__(256) void skip_gemm(
    const unsigned short* __restrict__ xb,
    const unsigned short* __restrict__ wb,
    const float* __restrict__ b_dec,
    float* __restrict__ out){
  __shared__ unsigned short As[128][32];
  __shared__ unsigned short Bs[64][32];
  const int row0 = blockIdx.x * 128;
  const int col0 = blockIdx.y * 64;
  const int t    = threadIdx.x;
  const int lane = t & 63;
  const int w    = t >> 6;
  const int wr   = w * 32;
  const int lm   = lane & 15;
  const int kq   = lane >> 4;
  const int sr   = t >> 2;
  const int sc   = (t & 3) * 8;

  floatx4 acc[2][4] = {};

  for (int k0 = 0; k0 < DIM; k0 += 32){
    __builtin_amdgcn_global_load_lds(GLOBAL_AS(xb + (size_t)(row0 + sr) * DIM + k0 + sc),
                                     LDS_AS(&As[sr][sc]), 16, 0, 0);
    __builtin_amdgcn_global_load_lds(GLOBAL_AS(xb + (size_t)(row0 + 64 + sr) * DIM + k0 + sc),
                                     LDS_AS(&As[64 + sr][sc]), 16, 0, 0);
    __builtin_amdgcn_global_load_lds(GLOBAL_AS(wb + (size_t)(col0 + sr) * DIM + k0 + sc),
                                     LDS_AS(&Bs[sr][sc]), 16, 0, 0);
    __syncthreads();
    bf16x8 af[2], bfr[4];
    #pragma unroll
    for (int mi = 0; mi < 2; mi++) af[mi] = *(const bf16x8*)(&As[wr + mi * 16 + lm][kq * 8]);
    #pragma unroll
    for (int ni = 0; ni < 4; ni++) bfr[ni] = *(const bf16x8*)(&Bs[ni * 16 + lm][kq * 8]);
    #pragma unroll
    for (int mi = 0; mi < 2; mi++)
      #pragma unroll
      for (int ni = 0; ni < 4; ni++)
        acc[mi][ni] = __builtin_amdgcn_mfma_f32_16x16x32_bf16(af[mi], bfr[ni], acc[mi][ni], 0, 0, 0);
    __syncthreads();
  }

  const int rq = (lane >> 4) * 4;   // C/D: col=lane&15, row=(lane>>4)*4+reg
  #pragma unroll
  for (int mi = 0; mi < 2; mi++){
    #pragma unroll
    for (int ni = 0; ni < 4; ni++){
      int col = col0 + ni * 16 + lm;
      float bd = b_dec[col];
      #pragma unroll
      for (int r = 0; r < 4; r++){
        int row = row0 + wr + mi * 16 + rq + r;
        out[(size_t)row * DIM + col] = acc[mi][ni][r] + bd;
      }
    }
  }
}

// Chunked decode. nt streaming keeps the 4 MB W_dec chunk resident in local XCD L2.
// Gather loop: EXPLICIT 8-deep batched pipeline (named regs, static indices) so the
// in-flight load depth does not depend on regalloc heuristics (round-1 lesson:
// VGPR dropped 60->32 and the compiler serialized the gathers -> 3x slowdown).
__global__ __launch_bounds__(256) void decode_residual(
    const float* __restrict__ y,
    const uint2* __restrict__ actbuf,
    const unsigned short* __restrict__ Wdc,  // [NCHUNK][NLAT][128] bf16
    float* __restrict__ out,
    float* __restrict__ accs,
    float* __restrict__ fvu_out){
  const int chunk = blockIdx.x & 7;          // == XCD id under round-robin dispatch
  const int tok0  = (blockIdx.x >> 3) * 16;
  const int t  = threadIdx.x;
  const int tl = t >> 4;       // token lane 0..15
  const int cl = t & 15;       // col lane (8 cols each)
  const int lane = t & 63, w = t >> 6;
  __shared__ uint2 s_ai[16][66];   // stride 66 -> conflict-free
  __shared__ float s_cs[4][16][8];
  __shared__ float s_red[4][2];
  __shared__ unsigned int s_last;

  #pragma unroll
  for (int i = 0; i < 4; i++){
    int e = t + i * 256;                 // (tok = e>>6, k = e&63)
    u32x2 v = __builtin_nontemporal_load((const u32x2*)&actbuf[tok0 * KTOP + e]);
    s_ai[e >> 6][e & 63] = make_uint2(v[0], v[1]);
  }
  const int n = tok0 + tl;
  const char* Wbase = (const char*)Wdc + (size_t)chunk * NLAT * 256 + cl * 16;
  float* op = out + (size_t)n * DIM + chunk * 128 + cl * 8;
  const float* yp = y + (size_t)n * DIM + chunk * 128 + cl * 8;
  f32x4 o0 = __builtin_nontemporal_load((const f32x4*)op);
  f32x4 o1 = __builtin_nontemporal_load((const f32x4*)op + 1);
  f32x4 y0 = __builtin_nontemporal_load((const f32x4*)yp);
  f32x4 y1 = __builtin_nontemporal_load((const f32x4*)yp + 1);
  __syncthreads();

  float a0 = 0.f, a1 = 0.f, a2 = 0.f, a3 = 0.f, a4 = 0.f, a5 = 0.f, a6 = 0.f, a7 = 0.f;
  #pragma unroll
  for (int kb = 0; kb < KTOP / 8; kb++){
    float av[8]; uint4 wv[8];
    #pragma unroll
    for (int j = 0; j < 8; j++){
      uint2 p = s_ai[tl][kb * 8 + j];
      av[j] = __uint_as_float(p.x);
      wv[j] = *(const uint4*)(Wbase + p.y);   // 8 gathers in flight per batch
    }
    #pragma unroll
    for (int j = 0; j < 8; j++){
      a0 += av[j] * bflo(wv[j].x); a1 += av[j] * bfhi(wv[j].x);
      a2 += av[j] * bflo(wv[j].y); a3 += av[j] * bfhi(wv[j].y);
      a4 += av[j] * bflo(wv[j].z); a5 += av[j] * bfhi(wv[j].z);
      a6 += av[j] * bflo(wv[j].w); a7 += av[j] * bfhi(wv[j].w);
    }
  }
  a0 += o0[0]; a1 += o0[1]; a2 += o0[2]; a3 += o0[3];
  a4 += o1[0]; a5 += o1[1]; a6 += o1[2]; a7 += o1[3];
  f32x4 r0 = {a0, a1, a2, a3};
  f32x4 r1 = {a4, a5, a6, a7};
  __builtin_nontemporal_store(r0, (f32x4*)op);
  __builtin_nontemporal_store(r1, (f32x4*)op + 1);

  float e0 = y0[0]-a0, e1 = y0[1]-a1, e2 = y0[2]-a2, e3 = y0[3]-a3;
  float e4 = y1[0]-a4, e5 = y1[1]-a5, e6 = y1[2]-a6, e7 = y1[3]-a7;
  float s  = e0*e0+e1*e1+e2*e2+e3*e3+e4*e4+e5*e5+e6*e6+e7*e7;
  float sq = y0[0]*y0[0]+y0[1]*y0[1]+y0[2]*y0[2]+y0[3]*y0[3]
           + y1[0]*y1[0]+y1[1]*y1[1]+y1[2]*y1[2]+y1[3]*y1[3];
  // colsum: reduce over the wave's 4 token-lanes (lanes differ in bits 4,5)
  float cs[8] = {y0[0], y0[1], y0[2], y0[3], y1[0], y1[1], y1[2], y1[3]};
  #pragma unroll
  for (int j = 0; j < 8; j++){
    cs[j] += __shfl_xor(cs[j], 16, 64);
    cs[j] += __shfl_xor(cs[j], 32, 64);
  }
  if (lane < 16){
    #pragma unroll
    for (int j = 0; j < 8; j++) s_cs[w][lane][j] = cs[j];
  }
  #pragma unroll
  for (int off = 32; off > 0; off >>= 1){
    s  += __shfl_down(s, off, 64);
    sq += __shfl_down(sq, off, 64);
  }
  if (lane == 0){ s_red[w][0] = s; s_red[w][1] = sq; }
  __syncthreads();
  if (t < 128){
    int c2 = t >> 3, j2 = t & 7;
    atomicAdd(&accs[4 + chunk * 128 + c2 * 8 + j2],
              s_cs[0][c2][j2] + s_cs[1][c2][j2] + s_cs[2][c2][j2] + s_cs[3][c2][j2]);
  }
  if (t == 0) atomicAdd(&accs[0], s_red[0][0] + s_red[1][0] + s_red[2][0] + s_red[3][0]);
  if (t == 1) atomicAdd(&accs[1], s_red[0][1] + s_red[1][1] + s_red[2][1] + s_red[3][1]);
  __syncthreads();   // barrier drains this block's atomics (vmcnt) before ticket
  if (t == 0){
    __threadfence();
    unsigned int done = atomicAdd((unsigned int*)&accs[2], 1u);
    s_last = (done == (unsigned int)(NCHUNK * (N_TOK / 16)) - 1u) ? 1u : 0u;
  }
  __syncthreads();
  if (s_last){
    __threadfence();
    float sp = 0.f;
    #pragma unroll
    for (int i = 0; i < 4; i++){
      float c = __hip_atomic_load(&accs[4 + t * 4 + i], __ATOMIC_RELAXED, __HIP_MEMORY_SCOPE_AGENT);
      sp += c * c;
    }
    #pragma unroll
    for (int off = 32; off > 0; off >>= 1) sp += __shfl_down(sp, off, 64);
    if (lane == 0) s_red[w][0] = sp;
    __syncthreads();
    if (t == 0){
      float ss    = s_red[0][0] + s_red[1][0] + s_red[2][0] + s_red[3][0];
      float sse_v = __hip_atomic_load(&accs[0], __ATOMIC_RELAXED, __HIP_MEMORY_SCOPE_AGENT);
      float sq_v  = __hip_atomic_load(&accs[1], __ATOMIC_RELAXED, __HIP_MEMORY_SCOPE_AGENT);
      fvu_out[0] = sse_v / (sq_v - ss / (float)N_TOK);
    }
  }
}

extern "C" void kernel_launch(void* const* d_in, const int* in_sizes, int n_in,
                              void* d_out, int out_size, void* d_ws, size_t ws_size,
                              hipStream_t stream){
  const float* x   = (const float*)d_in[0];
  const float* y   = (const float*)d_in[1];
  const float* la  = (const float*)d_in[2];
  const int*   li  = (const int*)d_in[3];
  const float* Wd  = (const float*)d_in[4];
  const float* bd  = (const float*)d_in[5];
  const float* pe  = (const float*)d_in[6];
  const float* pes = (const float*)d_in[7];
  const float* Wsk = (const float*)d_in[8];
  float* out = (float*)d_out;

  float* accs = (float*)d_ws;  // [0]=sse [1]=sumsq [2]=ticket [4..1028)=colsum
  unsigned short* xb  = (unsigned short*)((char*)d_ws + 8192);
  unsigned short* wb  = xb + (size_t)N_TOK * DIM;
  unsigned short* wdc = wb + (size_t)DIM * DIM;
  uint2* actbuf = (uint2*)(wdc + (size_t)NCHUNK * NLAT * 128);

  prep<<<5441, 256, 0, stream>>>(x, Wsk, Wd, la, li, pe, pes, xb, wb, wdc, actbuf, accs);
  skip_gemm<<<dim3(N_TOK / 128, DIM / 64), 256, 0, stream>>>(xb, wb, bd, out);
  decode_residual<<<(N_TOK / 16) * NCHUNK, 256, 0, stream>>>(y, actbuf, wdc, out, accs,
                                                             out + (size_t)N_TOK * DIM);
}

// Round 3
// 252.261 us; speedup vs baseline: 1.2629x; 1.2629x over previous
//
#include <hip/hip_runtime.h>
#include <hip/hip_bf16.h>
#include <cstdint>

#define N_TOK 4096
#define KTOP  64
#define DIM   1024
#define NLAT  16384
#define NCHUNK 8      // 128 cols/chunk -> 4 MB bf16 per chunk == one XCD L2

typedef __bf16 bf16x8 __attribute__((ext_vector_type(8)));
typedef float  floatx4 __attribute__((ext_vector_type(4)));
typedef float  f32x4   __attribute__((ext_vector_type(4)));
typedef unsigned int   u32x2   __attribute__((ext_vector_type(2)));
typedef unsigned short ushortx8 __attribute__((ext_vector_type(8)));

#define GLOBAL_AS(p) ((const __attribute__((address_space(1))) void*)(p))
#define LDS_AS(p)    ((__attribute__((address_space(3))) void*)(p))

__device__ inline unsigned short f2bf(float f){
  unsigned int u = __float_as_uint(f);
  unsigned int r = (u + 0x7fffu + ((u >> 16) & 1u)) >> 16;  // RNE
  return (unsigned short)r;
}
__device__ inline float bflo(unsigned int u){ return __uint_as_float(u << 16); }
__device__ inline float bfhi(unsigned int u){ return __uint_as_float(u & 0xffff0000u); }

// read 8 consecutive f32 (2x float4), write one 16B ushort8 bf16 store
__device__ inline void cvt8(const float* __restrict__ src, unsigned short* __restrict__ dst){
  float4 a = ((const float4*)src)[0];
  float4 b = ((const float4*)src)[1];
  ushortx8 o;
  o[0] = f2bf(a.x); o[1] = f2bf(a.y); o[2] = f2bf(a.z); o[3] = f2bf(a.w);
  o[4] = f2bf(b.x); o[5] = f2bf(b.y); o[6] = f2bf(b.z); o[7] = f2bf(b.w);
  *(ushortx8*)dst = o;
}

// Roles: [0,1024) x->bf16 | [1024,1280) Wskip->bf16 | [1280,5376) Wdec->chunked bf16
//        [5376,5440) act precompute | 5440: zero accumulators
__global__ __launch_bounds__(256) void prep(
    const float* __restrict__ x, const float* __restrict__ Wsk,
    const float* __restrict__ Wd,
    const float* __restrict__ la, const int* __restrict__ li,
    const float* __restrict__ pe, const float* __restrict__ pes,
    unsigned short* __restrict__ xb, unsigned short* __restrict__ wb,
    unsigned short* __restrict__ wdc,
    uint2* __restrict__ actbuf, float* __restrict__ accs){
  const int b = blockIdx.x;
  const int t = threadIdx.x;
  if (b < 1024){
    #pragma unroll
    for (int i = 0; i < 2; i++){
      int idx = b * 4096 + i * 2048 + t * 8;
      cvt8(x + idx, xb + idx);
    }
  } else if (b < 1280){
    #pragma unroll
    for (int i = 0; i < 2; i++){
      int idx = (b - 1024) * 4096 + i * 2048 + t * 8;
      cvt8(Wsk + idx, wb + idx);
    }
  } else if (b < 5376){
    const int j = t & 127;          // 128 threads per row, 8 floats each
    const int chunk = j >> 4;
    #pragma unroll
    for (int i = 0; i < 2; i++){
      int lat = (b - 1280) * 4 + i * 2 + (t >> 7);
      cvt8(Wd + (size_t)lat * DIM + j * 8,
           wdc + ((size_t)chunk * NLAT + lat) * 128 + (j & 15) * 8);
    }
  } else if (b < 5440){
    int e0 = (b - 5376) * 4096 + t;
    #pragma unroll
    for (int i = 0; i < 16; i++){
      int e = e0 + i * 256;
      int id = li[e];
      float a = (la[e] + pe[id]) * pes[id];
      actbuf[e] = make_uint2(__float_as_uint(a), (unsigned)id * 256u);
    }
  } else {
    for (int i = t; i < 1056; i += 256) accs[i] = 0.f;  // sse, sumsq, (pad), colsum
  }
}

// 128 rows x 64 cols tile -> 512 blocks (2 blocks/CU). m97-style staging. (unchanged)
__global__ __launch_bounds__(256) void skip_gemm(
    const unsigned short* __restrict__ xb,
    const unsigned short* __restrict__ wb,
    const float* __restrict__ b_dec,
    float* __restrict__ out){
  __shared__ unsigned short As[128][32];
  __shared__ unsigned short Bs[64][32];
  const int row0 = blockIdx.x * 128;
  const int col0 = blockIdx.y * 64;
  const int t    = threadIdx.x;
  const int lane = t & 63;
  const int w    = t >> 6;
  const int wr   = w * 32;
  const int lm   = lane & 15;
  const int kq   = lane >> 4;
  const int sr   = t >> 2;
  const int sc   = (t & 3) * 8;

  floatx4 acc[2][4] = {};

  for (int k0 = 0; k0 < DIM; k0 += 32){
    __builtin_amdgcn_global_load_lds(GLOBAL_AS(xb + (size_t)(row0 + sr) * DIM + k0 + sc),
                                     LDS_AS(&As[sr][sc]), 16, 0, 0);
    __builtin_amdgcn_global_load_lds(GLOBAL_AS(xb + (size_t)(row0 + 64 + sr) * DIM + k0 + sc),
                                     LDS_AS(&As[64 + sr][sc]), 16, 0, 0);
    __builtin_amdgcn_global_load_lds(GLOBAL_AS(wb + (size_t)(col0 + sr) * DIM + k0 + sc),
                                     LDS_AS(&Bs[sr][sc]), 16, 0, 0);
    __syncthreads();
    bf16x8 af[2], bfr[4];
    #pragma unroll
    for (int mi = 0; mi < 2; mi++) af[mi] = *(const bf16x8*)(&As[wr + mi * 16 + lm][kq * 8]);
    #pragma unroll
    for (int ni = 0; ni < 4; ni++) bfr[ni] = *(const bf16x8*)(&Bs[ni * 16 + lm][kq * 8]);
    #pragma unroll
    for (int mi = 0; mi < 2; mi++)
      #pragma unroll
      for (int ni = 0; ni < 4; ni++)
        acc[mi][ni] = __builtin_amdgcn_mfma_f32_16x16x32_bf16(af[mi], bfr[ni], acc[mi][ni], 0, 0, 0);
    __syncthreads();
  }

  const int rq = (lane >> 4) * 4;   // C/D: col=lane&15, row=(lane>>4)*4+reg
  #pragma unroll
  for (int mi = 0; mi < 2; mi++){
    #pragma unroll
    for (int ni = 0; ni < 4; ni++){
      int col = col0 + ni * 16 + lm;
      float bd = b_dec[col];
      #pragma unroll
      for (int r = 0; r < 4; r++){
        int row = row0 + wr + mi * 16 + rq + r;
        out[(size_t)row * DIM + col] = acc[mi][ni][r] + bd;
      }
    }
  }
}

// Chunked decode. nt streaming keeps the 4 MB W_dec chunk resident in local XCD L2.
// NO fences/tickets here: __threadfence() at agent scope emits buffer_inv -> wipes the
// XCD L2 every block epilogue, which is what destroyed rounds 1-2 (gathers fell to L3,
// 51 -> 150 us). FVU finalize is a separate tiny kernel; end-of-dispatch release gives
// visibility. All reductions use plain relaxed atomicAdd (no cache maintenance).
__global__ __launch_bounds__(256) void decode_residual(
    const float* __restrict__ y,
    const uint2* __restrict__ actbuf,
    const unsigned short* __restrict__ Wdc,  // [NCHUNK][NLAT][128] bf16
    float* __restrict__ out,
    float* __restrict__ accs){
  const int chunk = blockIdx.x & 7;          // == XCD id under round-robin dispatch
  const int tok0  = (blockIdx.x >> 3) * 16;
  const int t  = threadIdx.x;
  const int tl = t >> 4;       // token lane 0..15
  const int cl = t & 15;       // col lane (8 cols each)
  const int lane = t & 63, w = t >> 6;
  __shared__ uint2 s_ai[16][66];   // stride 66 -> conflict-free
  __shared__ float s_cs[4][16][8];
  __shared__ float s_red[4][2];

  #pragma unroll
  for (int i = 0; i < 4; i++){
    int e = t + i * 256;                 // (tok = e>>6, k = e&63)
    u32x2 v = __builtin_nontemporal_load((const u32x2*)&actbuf[tok0 * KTOP + e]);
    s_ai[e >> 6][e & 63] = make_uint2(v[0], v[1]);
  }
  const int n = tok0 + tl;
  const char* Wbase = (const char*)Wdc + (size_t)chunk * NLAT * 256 + cl * 16;
  float* op = out + (size_t)n * DIM + chunk * 128 + cl * 8;
  const float* yp = y + (size_t)n * DIM + chunk * 128 + cl * 8;
  f32x4 o0 = __builtin_nontemporal_load((const f32x4*)op);
  f32x4 o1 = __builtin_nontemporal_load((const f32x4*)op + 1);
  f32x4 y0 = __builtin_nontemporal_load((const f32x4*)yp);
  f32x4 y1 = __builtin_nontemporal_load((const f32x4*)yp + 1);
  __syncthreads();

  float a0 = 0.f, a1 = 0.f, a2 = 0.f, a3 = 0.f, a4 = 0.f, a5 = 0.f, a6 = 0.f, a7 = 0.f;
  #pragma unroll
  for (int kb = 0; kb < KTOP / 8; kb++){
    float av[8]; uint4 wv[8];
    #pragma unroll
    for (int j = 0; j < 8; j++){
      uint2 p = s_ai[tl][kb * 8 + j];
      av[j] = __uint_as_float(p.x);
      wv[j] = *(const uint4*)(Wbase + p.y);   // 8 gathers in flight per batch
    }
    #pragma unroll
    for (int j = 0; j < 8; j++){
      a0 += av[j] * bflo(wv[j].x); a1 += av[j] * bfhi(wv[j].x);
      a2 += av[j] * bflo(wv[j].y); a3 += av[j] * bfhi(wv[j].y);
      a4 += av[j] * bflo(wv[j].z); a5 += av[j] * bfhi(wv[j].z);
      a6 += av[j] * bflo(wv[j].w); a7 += av[j] * bfhi(wv[j].w);
    }
  }
  a0 += o0[0]; a1 += o0[1]; a2 += o0[2]; a3 += o0[3];
  a4 += o1[0]; a5 += o1[1]; a6 += o1[2]; a7 += o1[3];
  f32x4 r0 = {a0, a1, a2, a3};
  f32x4 r1 = {a4, a5, a6, a7};
  __builtin_nontemporal_store(r0, (f32x4*)op);
  __builtin_nontemporal_store(r1, (f32x4*)op + 1);

  float e0 = y0[0]-a0, e1 = y0[1]-a1, e2 = y0[2]-a2, e3 = y0[3]-a3;
  float e4 = y1[0]-a4, e5 = y1[1]-a5, e6 = y1[2]-a6, e7 = y1[3]-a7;
  float s  = e0*e0+e1*e1+e2*e2+e3*e3+e4*e4+e5*e5+e6*e6+e7*e7;
  float sq = y0[0]*y0[0]+y0[1]*y0[1]+y0[2]*y0[2]+y0[3]*y0[3]
           + y1[0]*y1[0]+y1[1]*y1[1]+y1[2]*y1[2]+y1[3]*y1[3];
  // colsum: reduce over the wave's 4 token-lanes (lanes differ in bits 4,5)
  float cs[8] = {y0[0], y0[1], y0[2], y0[3], y1[0], y1[1], y1[2], y1[3]};
  #pragma unroll
  for (int j = 0; j < 8; j++){
    cs[j] += __shfl_xor(cs[j], 16, 64);
    cs[j] += __shfl_xor(cs[j], 32, 64);
  }
  if (lane < 16){
    #pragma unroll
    for (int j = 0; j < 8; j++) s_cs[w][lane][j] = cs[j];
  }
  #pragma unroll
  for (int off = 32; off > 0; off >>= 1){
    s  += __shfl_down(s, off, 64);
    sq += __shfl_down(sq, off, 64);
  }
  if (lane == 0){ s_red[w][0] = s; s_red[w][1] = sq; }
  __syncthreads();
  if (t < 128){
    int c2 = t >> 3, j2 = t & 7;
    atomicAdd(&accs[4 + chunk * 128 + c2 * 8 + j2],
              s_cs[0][c2][j2] + s_cs[1][c2][j2] + s_cs[2][c2][j2] + s_cs[3][c2][j2]);
  }
  if (t == 0) atomicAdd(&accs[0], s_red[0][0] + s_red[1][0] + s_red[2][0] + s_red[3][0]);
  if (t == 1) atomicAdd(&accs[1], s_red[0][1] + s_red[1][1] + s_red[2][1] + s_red[3][1]);
}

// Tiny finalize: fvu = sse / (sumsq - sum(colsum^2)/N). Kernel boundary gives visibility.
__global__ __launch_bounds__(256) void fvu_kernel(
    const float* __restrict__ ws, float* __restrict__ fvu_out){
  const int t = threadIdx.x;
  float4 c = ((const float4*)(ws + 4))[t];
  float s = c.x*c.x + c.y*c.y + c.z*c.z + c.w*c.w;
  #pragma unroll
  for (int off = 32; off > 0; off >>= 1) s += __shfl_down(s, off, 64);
  __shared__ float s_red[4];
  if ((t & 63) == 0) s_red[t >> 6] = s;
  __syncthreads();
  if (t == 0){
    float ss = s_red[0] + s_red[1] + s_red[2] + s_red[3];
    float tv = ws[1] - ss / (float)N_TOK;
    fvu_out[0] = ws[0] / tv;
  }
}

extern "C" void kernel_launch(void* const* d_in, const int* in_sizes, int n_in,
                              void* d_out, int out_size, void* d_ws, size_t ws_size,
                              hipStream_t stream){
  const float* x   = (const float*)d_in[0];
  const float* y   = (const float*)d_in[1];
  const float* la  = (const float*)d_in[2];
  const int*   li  = (const int*)d_in[3];
  const float* Wd  = (const float*)d_in[4];
  const float* bd  = (const float*)d_in[5];
  const float* pe  = (const float*)d_in[6];
  const float* pes = (const float*)d_in[7];
  const float* Wsk = (const float*)d_in[8];
  float* out = (float*)d_out;

  float* accs = (float*)d_ws;  // [0]=sse [1]=sumsq [4..1028)=colsum
  unsigned short* xb  = (unsigned short*)((char*)d_ws + 8192);
  unsigned short* wb  = xb + (size_t)N_TOK * DIM;
  unsigned short* wdc = wb + (size_t)DIM * DIM;
  uint2* actbuf = (uint2*)(wdc + (size_t)NCHUNK * NLAT * 128);

  prep<<<5441, 256, 0, stream>>>(x, Wsk, Wd, la, li, pe, pes, xb, wb, wdc, actbuf, accs);
  skip_gemm<<<dim3(N_TOK / 128, DIM / 64), 256, 0, stream>>>(xb, wb, bd, out);
  decode_residual<<<(N_TOK / 16) * NCHUNK, 256, 0, stream>>>(y, actbuf, wdc, out, accs);
  fvu_kernel<<<1, 256, 0, stream>>>(accs, out + (size_t)N_TOK * DIM);
}